// Round 21
// baseline (197.558 us; speedup 1.0000x reference)
//
#include <hip/hip_runtime.h>
#include <hip/hip_bf16.h>
#include <cstdint>
#include <cstddef>

typedef __attribute__((ext_vector_type(8))) short short8;
typedef __attribute__((ext_vector_type(4))) float floatx4;
typedef __attribute__((ext_vector_type(16))) float floatx16;

#define B_ 32
#define H_ 8
#define D_ 512
#define DH_ 64
#define SQ_ 512
#define SK_ 512
#define NEG_INF_ -1000000000.0f
#define LOG2E_ 1.4426950408889634f
#define FIXED_MAX_ 24.0f

__device__ __forceinline__ short f2bf(float f) {
  union { float f; uint32_t u; } x; x.f = f;
  uint32_t r = x.u + 0x7FFFu + ((x.u >> 16) & 1u);
  return (short)(r >> 16);
}
__device__ __forceinline__ uint32_t cvt_pk_bf16(float lo, float hi) {
  uint32_t r;
  asm("v_cvt_pk_bf16_f32 %0, %1, %2" : "=v"(r) : "v"(lo), "v"(hi));
  return r;
}
// Swap upper-half lanes of a with lower-half lanes of b (both modified).
__device__ __forceinline__ void plane32_swap(uint32_t& a, uint32_t& b) {
  asm("v_permlane32_swap_b32 %0, %1" : "+v"(a), "+v"(b));
}

// Small prep (256 thr), role by blockIdx.x:
//   0..31 : bias row for b = id (mask-layout detect folded in, block-local)
//   32    : msv
//   33..288: W -> bf16
__global__ __launch_bounds__(256) void smallprep_kernel(
    const uint8_t* __restrict__ mask8,
    float* __restrict__ kbias,
    const float* __restrict__ m_v, const float* __restrict__ s_v,
    float2* __restrict__ msv,
    const float* __restrict__ W, short* __restrict__ Wb)
{
  __shared__ int fnd;
  const int id = blockIdx.x, tid = threadIdx.x;

  if (id < 32) {
    if (tid == 0) fnd = 0;
    __syncthreads();
    int any = 0;
    for (int i = tid; i < B_ * SK_; i += 256)
      if ((i & 3) != 0 && mask8[i] != 0) any = 1;
    if (any) atomicOr(&fnd, 1);
    __syncthreads();
    const int fl = fnd;

    const int b = id;
    for (int j = 0; j < 2; ++j) {
      const int kk = j * 256 + tid;
      int mv;
      if (fl) mv = mask8[b * SK_ + kk];
      else    mv = reinterpret_cast<const int*>(mask8)[b * SK_ + kk];
      kbias[b * SK_ + kk] = mv ? NEG_INF_ * LOG2E_ : 0.0f;
    }
  } else if (id == 32) {
    for (int j = 0; j < 2; ++j) {
      const int d = j * 256 + tid;
      const float inv = 1.0f / s_v[d];
      msv[d] = make_float2(inv, m_v[d] * inv);
    }
  } else {
    const int i = (id - 33) * 256 + tid;
    const float4 f = reinterpret_cast<const float4*>(W)[i];
    short4 s;
    s.x = f2bf(f.x); s.y = f2bf(f.y); s.z = f2bf(f.z); s.w = f2bf(f.w);
    reinterpret_cast<short4*>(Wb)[i] = s;
  }
}

// Swapped-operand 32x32 flash attention, phase-split staging.
// ONE block per (b,h): 1024 threads / 16 waves; LDS 130 KB caps residency at
// 1 block/CU regardless of VGPRs, so launch_bounds(1024,2) relaxes the
// register cap (fixes r20's spills) at zero occupancy cost.
// 4 phases x 2 tiles: each phase issues the NEXT pair's staging (K transpose
// + V copy from f32), computes the current pair, then full drain+barrier.
__global__ __launch_bounds__(1024, 2) void attn_kernel(
    const float* __restrict__ qf32,     // [B][D][SQ] f32
    short* __restrict__ xqT,            // out x: [B][H][SQ][64] bf16
    const float* __restrict__ kf32,     // [B][D][SK] f32
    const float* __restrict__ vf32,     // [B][D][SK] f32
    const float* __restrict__ gamma, const float* __restrict__ beta,
    const float* __restrict__ m_qk, const float* __restrict__ s_qk,
    const float2* __restrict__ msv, const float* __restrict__ kbias)
{
  __shared__ float bias_s[SK_];
  __shared__ short kbuf[8][4096];       // per 64-tile: [64 k-rows][64 d] swizzled
  __shared__ short vbuf[8][4096];       // per 64-tile: [64 d-rows][64 k] swizzled

  const int bh = blockIdx.x;            // 0..255
  const int h = bh & 7, b = bh >> 3;

  const int tid = threadIdx.x, w = tid >> 6, l = tid & 63;
  const int l31 = l & 31, hi = l >> 5;
  const int swz = l31 & 7;

  const float gh = gamma[h], be = beta[h], mq = m_qk[h], sq = s_qk[h];
  const float a2 = gh / (sq * 8.0f) * LOG2E_;
  const float c2 = (be - mq * gh / sq) * LOG2E_ - FIXED_MAX_;

  const int qidx = w * 32 + l31;
  const float* kfb = kf32 + ((size_t)b * D_ + h * DH_) * (size_t)SK_;
  const float* vbase = vf32 + ((size_t)b * D_ + h * DH_) * (size_t)SK_;
  const float* qsrc = qf32 + ((size_t)b * D_ + h * DH_) * (size_t)SQ_ + qidx;

  // staging lane geometry
  const int dsub = l >> 3, ksub = l & 7;          // K-waves
  const int rsub = l >> 3;                        // V-waves
  const int c16s = (l & 7) ^ rsub;
  const int ck = w & 7;
  const float* kp0 = kfb + (size_t)(w * 8 + dsub) * SK_ + ksub;

  // stage tiles 2*pp and 2*pp+1 (K-waves transpose; V-waves vector copy)
  auto stage_pair = [&](int pp) {
#pragma unroll
    for (int tt = 0; tt < 2; ++tt) {
      const int t = pp * 2 + tt;
      if (w < 8) {
        float fv[8];
#pragma unroll
        for (int kk = 0; kk < 8; ++kk)
          fv[kk] = kp0[t * 64 + kk * 8];
        short* kb = kbuf[t];
#pragma unroll
        for (int kk = 0; kk < 8; ++kk)
          kb[(kk * 8 + ksub) * 64 + ((w ^ ksub) << 3) + dsub] = f2bf(fv[kk]);
      } else {
        const float* vp = vbase + (size_t)(ck * 8 + rsub) * SK_ + t * 64 + c16s * 8;
        const float4 a = *reinterpret_cast<const float4*>(vp);
        const float4 c = *reinterpret_cast<const float4*>(vp + 4);
        union { uint32_t u[4]; short8 s; } pk;
        pk.u[0] = cvt_pk_bf16(a.x, a.y);
        pk.u[1] = cvt_pk_bf16(a.z, a.w);
        pk.u[2] = cvt_pk_bf16(c.x, c.y);
        pk.u[3] = cvt_pk_bf16(c.z, c.w);
        *reinterpret_cast<short8*>(&vbuf[t][ck * 512 + l * 8]) = pk.s;
      }
    }
  };

  stage_pair(0);                        // tiles 0,1 in flight

  // bias row to LDS (threads 0..127)
  if (tid < 128) {
    floatx4 t = reinterpret_cast<const floatx4*>(kbias + (size_t)b * SK_)[tid];
    t += c2;                             // fold affine offset + fixed max
    reinterpret_cast<floatx4*>(bias_s)[tid] = t;
  }

  // Q fragments (B-operand) direct from f32 (latency overlaps staging)
  short8 qf[4];
  for (int st = 0; st < 4; ++st) {
    float fv[8];
    for (int j = 0; j < 8; ++j)
      fv[j] = qsrc[(size_t)(st * 16 + hi * 8 + j) * SQ_];
    union { uint32_t u[4]; short8 s; } qk;
    for (int j2 = 0; j2 < 4; ++j2)
      qk.u[j2] = cvt_pk_bf16(fv[2 * j2], fv[2 * j2 + 1]);
    qf[st] = qk.s;
  }

  floatx16 oacc[2];
  for (int i = 0; i < 16; ++i) { oacc[0][i] = 0.f; oacc[1][i] = 0.f; }
  float lpart = 0.f;

  // phase-0 entry: tiles 0,1 (and bias) complete
  asm volatile("s_waitcnt vmcnt(0) lgkmcnt(0)" ::: "memory");
  __builtin_amdgcn_s_barrier();
  __builtin_amdgcn_sched_barrier(0);

#pragma unroll
  for (int p = 0; p < 4; ++p) {
    if (p < 3) stage_pair(p + 1);       // issue tiles 2p+2, 2p+3

#pragma unroll
    for (int tt = 0; tt < 2; ++tt) {
      const int it = p * 2 + tt;
      const int k0 = it * 64;
      const short* kl = kbuf[it];
      const short* vl = vbuf[it];

      // ---- S^T = K Q ----
      floatx16 s0, s1;
      for (int i = 0; i < 16; ++i) { s0[i] = 0.f; s1[i] = 0.f; }
      __builtin_amdgcn_s_setprio(1);
      for (int st = 0; st < 4; ++st) {
        const short8 ka = *reinterpret_cast<const short8*>(
            &kl[(size_t)l31 * 64 + (((st << 1) | hi) ^ swz) * 8]);
        s0 = __builtin_amdgcn_mfma_f32_32x32x16_bf16(ka, qf[st], s0, 0, 0, 0);
      }
      for (int st = 0; st < 4; ++st) {
        const short8 kb = *reinterpret_cast<const short8*>(
            &kl[(size_t)(32 + l31) * 64 + (((st << 1) | hi) ^ swz) * 8]);
        s1 = __builtin_amdgcn_mfma_f32_32x32x16_bf16(kb, qf[st], s1, 0, 0, 0);
      }
      __builtin_amdgcn_s_setprio(0);

      // P = exp2(s*a2 + bias)
      float p2[32];
      for (int sub = 0; sub < 2; ++sub)
        for (int gg = 0; gg < 4; ++gg) {
          const floatx4 bv = *reinterpret_cast<const floatx4*>(
              &bias_s[k0 + sub * 32 + gg * 8 + hi * 4]);
          for (int r = 0; r < 4; ++r) {
            const float sc = sub ? s1[gg * 4 + r] : s0[gg * 4 + r];
            p2[sub * 16 + gg * 4 + r] =
                __builtin_amdgcn_exp2f(__builtin_fmaf(sc, a2, bv[r]));
          }
        }

      // partial row-sum
      {
        float a16[16];
        for (int i = 0; i < 16; ++i) a16[i] = p2[i] + p2[i + 16];
        float a8[8];
        for (int i = 0; i < 8; ++i) a8[i] = a16[i] + a16[i + 8];
        lpart += ((a8[0] + a8[4]) + (a8[1] + a8[5])) + ((a8[2] + a8[6]) + (a8[3] + a8[7]));
      }

      // P -> bf16 words
      uint32_t Wd[16];
      for (int j = 0; j < 16; ++j) Wd[j] = cvt_pk_bf16(p2[2 * j], p2[2 * j + 1]);

      // PV with permlane32_swap cross-half exchange
      __builtin_amdgcn_s_setprio(1);
      for (int kc = 0; kc < 4; ++kc) {
        const int base = (kc >> 1) * 8 + (kc & 1) * 4;
        uint32_t x0 = Wd[base + 0], x1 = Wd[base + 1];
        uint32_t y0 = Wd[base + 2], y1 = Wd[base + 3];
        plane32_swap(x0, y0);
        plane32_swap(x1, y1);
        union { uint32_t u[4]; short8 s; } pk;
        pk.u[0] = x0; pk.u[1] = x1; pk.u[2] = y0; pk.u[3] = y1;
        const short8 pb = pk.s;
        const short8 va0 = *reinterpret_cast<const short8*>(
            &vl[(size_t)l31 * 64 + (((kc << 1) | hi) ^ swz) * 8]);
        const short8 va1 = *reinterpret_cast<const short8*>(
            &vl[(size_t)(32 + l31) * 64 + (((kc << 1) | hi) ^ swz) * 8]);
        oacc[0] = __builtin_amdgcn_mfma_f32_32x32x16_bf16(va0, pb, oacc[0], 0, 0, 0);
        oacc[1] = __builtin_amdgcn_mfma_f32_32x32x16_bf16(va1, pb, oacc[1], 0, 0, 0);
      }
      __builtin_amdgcn_s_setprio(0);
    }

    // phase boundary: next pair fully staged (order-robust full drain)
    if (p < 3) {
      asm volatile("s_waitcnt vmcnt(0) lgkmcnt(0)" ::: "memory");
      __builtin_amdgcn_s_barrier();
      __builtin_amdgcn_sched_barrier(0);
    }
  }

  lpart += __shfl_xor(lpart, 32, 64);

  // epilogue
  const float invl = __builtin_amdgcn_rcpf(lpart);
  short* xr = xqT + ((size_t)bh * SQ_ + qidx) * 64;
  const float2* msvh = msv + h * DH_;
  for (int dt = 0; dt < 2; ++dt)
    for (int gg = 0; gg < 4; ++gg) {
      const int d0 = dt * 32 + gg * 8 + hi * 4;
      float qv[4];
      for (int r = 0; r < 4; ++r) qv[r] = qsrc[(size_t)(d0 + r) * SQ_];
      const float2 c0 = msvh[d0 + 0], c1 = msvh[d0 + 1],
                   c2v = msvh[d0 + 2], c3 = msvh[d0 + 3];
      short4 xv;
      xv.x = f2bf((qv[0] + oacc[dt][gg * 4 + 0] * invl) * c0.x - c0.y);
      xv.y = f2bf((qv[1] + oacc[dt][gg * 4 + 1] * invl) * c1.x - c1.y);
      xv.z = f2bf((qv[2] + oacc[dt][gg * 4 + 2] * invl) * c2v.x - c2v.y);
      xv.w = f2bf((qv[3] + oacc[dt][gg * 4 + 3] * invl) * c3.x - c3.y);
      *reinterpret_cast<short4*>(xr + d0) = xv;
    }
}

// proj (r12 shape): out[b,o,q] = silu(bias[o] + sum_d W[o,d] x[b,q,d]).
// 256 thr / 4 waves, 256o x 64q block, 64 KB swizzled x-tile in LDS.
__global__ __launch_bounds__(256) void proj_kernel(
    const short* __restrict__ Wb, const short* __restrict__ xT,
    const float* __restrict__ bias, float* __restrict__ out)
{
  __shared__ short xs[64 * 512];
  const int q0 = blockIdx.x * 64;
  const int o0 = blockIdx.y * 256;
  const int b  = blockIdx.z;
  const int tid = threadIdx.x, w = tid >> 6, l = tid & 63;
  const int l15 = l & 15, g = l >> 4;

  const short* xb = xT + (size_t)b * (H_ * SQ_ * 64);
  for (int hh = w * 2; hh < w * 2 + 2; ++hh) {
    const short* src = xb + ((size_t)hh * SQ_ + q0) * 64;
    for (int j = 0; j < 8; ++j) {
      const short8 val = *reinterpret_cast<const short8*>(src + j * 512 + l * 8);
      const int row = j * 8 + (l >> 3);
      const int c16 = (hh * 8 + (l & 7)) ^ (row & 7);
      *reinterpret_cast<short8*>(&xs[row * 512 + c16 * 8]) = val;
    }
  }
  __syncthreads();

  floatx4 acc[4][4];
  for (int ai = 0; ai < 4; ++ai)
    for (int bj = 0; bj < 4; ++bj)
      acc[ai][bj] = floatx4{0.f, 0.f, 0.f, 0.f};

  const short* wbase = Wb + (size_t)(o0 + w * 64 + l15) * D_;

  for (int step = 0; step < 16; ++step) {
    short8 af[4];
    for (int ai = 0; ai < 4; ++ai)
      af[ai] = *reinterpret_cast<const short8*>(
          wbase + (size_t)(ai * 16) * D_ + step * 32 + g * 8);
    short8 bf[4];
    for (int bj = 0; bj < 4; ++bj) {
      const int row = bj * 16 + l15;
      const int c16 = (step * 4 + g) ^ (row & 7);
      bf[bj] = *reinterpret_cast<const short8*>(&xs[row * 512 + c16 * 8]);
    }
    for (int ai = 0; ai < 4; ++ai)
      for (int bj = 0; bj < 4; ++bj)
        acc[ai][bj] = __builtin_amdgcn_mfma_f32_16x16x32_bf16(af[ai], bf[bj],
                                                              acc[ai][bj], 0, 0, 0);
  }

  for (int ai = 0; ai < 4; ++ai)
    for (int r = 0; r < 4; ++r) {
      const int o = o0 + w * 64 + ai * 16 + g * 4 + r;
      const float bo = bias[o];
      float* orow = out + ((size_t)b * D_ + o) * SQ_ + q0;
      for (int bj = 0; bj < 4; ++bj) {
        const float val = acc[ai][bj][r] + bo;
        const float e = __builtin_amdgcn_exp2f(-val * LOG2E_);
        orow[bj * 16 + l15] = val * __builtin_amdgcn_rcpf(1.0f + e);
      }
    }
}

extern "C" void kernel_launch(void* const* d_in, const int* in_sizes, int n_in,
                              void* d_out, int out_size, void* d_ws, size_t ws_size,
                              hipStream_t stream) {
  const float*   q     = (const float*)d_in[0];
  const float*   k     = (const float*)d_in[1];
  const float*   v     = (const float*)d_in[2];
  const uint8_t* mask  = (const uint8_t*)d_in[3];
  const float*   gamma = (const float*)d_in[4];
  const float*   beta  = (const float*)d_in[5];
  const float*   m_qk  = (const float*)d_in[6];
  const float*   s_qk  = (const float*)d_in[7];
  const float*   m_v   = (const float*)d_in[8];
  const float*   s_v   = (const float*)d_in[9];
  const float*   W     = (const float*)d_in[10];
  const float*   bias  = (const float*)d_in[11];
  float* out = (float*)d_out;

  char* ws = (char*)d_ws;
  short*  Wb    = (short*)ws;                                   // 512 KB
  short*  xqT   = (short*)(ws + (1u << 19));                    // 16 MB (x output)
  float2* msv   = (float2*)(ws + (1u << 19) + 3u * (1u << 24)); // 4 KB
  float*  kbias = (float*)(ws + (1u << 19) + 3u * (1u << 24) + 8192); // 64 KB

  smallprep_kernel<<<289, 256, 0, stream>>>(mask, kbias, m_v, s_v, msv, W, Wb);
  attn_kernel<<<256, 1024, 0, stream>>>(q, xqT, k, v, gamma, beta,
                                        m_qk, s_qk, msv, kbias);
  proj_kernel<<<dim3(8, 2, 32), 256, 0, stream>>>(Wb, xqT, bias, out);
}

// Round 22
// 84.637 us; speedup vs baseline: 2.3342x; 2.3342x over previous
//
#include <hip/hip_runtime.h>
#include <hip/hip_bf16.h>
#include <cstdint>
#include <cstddef>

typedef __attribute__((ext_vector_type(8))) short short8;
typedef __attribute__((ext_vector_type(4))) float floatx4;
typedef __attribute__((ext_vector_type(16))) float floatx16;

#define B_ 32
#define H_ 8
#define D_ 512
#define DH_ 64
#define SQ_ 512
#define SK_ 512
#define NEG_INF_ -1000000000.0f
#define LOG2E_ 1.4426950408889634f
#define FIXED_MAX_ 24.0f

__device__ __forceinline__ short f2bf(float f) {
  union { float f; uint32_t u; } x; x.f = f;
  uint32_t r = x.u + 0x7FFFu + ((x.u >> 16) & 1u);
  return (short)(r >> 16);
}
__device__ __forceinline__ uint32_t cvt_pk_bf16(float lo, float hi) {
  uint32_t r;
  asm("v_cvt_pk_bf16_f32 %0, %1, %2" : "=v"(r) : "v"(lo), "v"(hi));
  return r;
}
// Swap upper-half lanes of a with lower-half lanes of b (both modified).
__device__ __forceinline__ void plane32_swap(uint32_t& a, uint32_t& b) {
  asm("v_permlane32_swap_b32 %0, %1" : "+v"(a), "+v"(b));
}

// Small prep (256 thr), role by blockIdx.x:
//   0..31 : bias row for b = id (mask-layout detect folded in, block-local)
//   32    : msv
//   33..288: W -> bf16
__global__ __launch_bounds__(256) void smallprep_kernel(
    const uint8_t* __restrict__ mask8,
    float* __restrict__ kbias,
    const float* __restrict__ m_v, const float* __restrict__ s_v,
    float2* __restrict__ msv,
    const float* __restrict__ W, short* __restrict__ Wb)
{
  __shared__ int fnd;
  const int id = blockIdx.x, tid = threadIdx.x;

  if (id < 32) {
    if (tid == 0) fnd = 0;
    __syncthreads();
    int any = 0;
    for (int i = tid; i < B_ * SK_; i += 256)
      if ((i & 3) != 0 && mask8[i] != 0) any = 1;
    if (any) atomicOr(&fnd, 1);
    __syncthreads();
    const int fl = fnd;

    const int b = id;
    for (int j = 0; j < 2; ++j) {
      const int kk = j * 256 + tid;
      int mv;
      if (fl) mv = mask8[b * SK_ + kk];
      else    mv = reinterpret_cast<const int*>(mask8)[b * SK_ + kk];
      kbias[b * SK_ + kk] = mv ? NEG_INF_ * LOG2E_ : 0.0f;
    }
  } else if (id == 32) {
    for (int j = 0; j < 2; ++j) {
      const int d = j * 256 + tid;
      const float inv = 1.0f / s_v[d];
      msv[d] = make_float2(inv, m_v[d] * inv);
    }
  } else {
    const int i = (id - 33) * 256 + tid;
    const float4 f = reinterpret_cast<const float4*>(W)[i];
    short4 s;
    s.x = f2bf(f.x); s.y = f2bf(f.y); s.z = f2bf(f.z); s.w = f2bf(f.w);
    reinterpret_cast<short4*>(Wb)[i] = s;
  }
}

// Swapped-operand 32x32 flash attention (r19 configuration, reverted).
// ONE block per (b,h): 1024 threads / 16 waves. BOTH K and V staged directly
// from f32 up front (K-waves transpose via ds_write_b16, V-waves vector copy);
// single order-robust vmcnt(0)+lgkmcnt(0)+barrier; no in-loop sync.
__global__ __launch_bounds__(1024, 4) void attn_kernel(
    const float* __restrict__ qf32,     // [B][D][SQ] f32
    short* __restrict__ xqT,            // out x: [B][H][SQ][64] bf16
    const float* __restrict__ kf32,     // [B][D][SK] f32
    const float* __restrict__ vf32,     // [B][D][SK] f32
    const float* __restrict__ gamma, const float* __restrict__ beta,
    const float* __restrict__ m_qk, const float* __restrict__ s_qk,
    const float2* __restrict__ msv, const float* __restrict__ kbias)
{
  __shared__ float bias_s[SK_];
  __shared__ short kbuf[8][4096];       // per 64-tile: [64 k-rows][64 d] swizzled
  __shared__ short vbuf[8][4096];       // per 64-tile: [64 d-rows][64 k] swizzled

  const int bh = blockIdx.x;            // 0..255
  const int h = bh & 7, b = bh >> 3;

  const int tid = threadIdx.x, w = tid >> 6, l = tid & 63;
  const int l31 = l & 31, hi = l >> 5;
  const int swz = l31 & 7;

  const float gh = gamma[h], be = beta[h], mq = m_qk[h], sq = s_qk[h];
  const float a2 = gh / (sq * 8.0f) * LOG2E_;
  const float c2 = (be - mq * gh / sq) * LOG2E_ - FIXED_MAX_;

  const int qidx = w * 32 + l31;
  const float* kfb = kf32 + ((size_t)b * D_ + h * DH_) * (size_t)SK_;
  const float* vbase = vf32 + ((size_t)b * D_ + h * DH_) * (size_t)SK_;
  const float* qsrc = qf32 + ((size_t)b * D_ + h * DH_) * (size_t)SQ_ + qidx;

  // bias row to LDS (threads 0..127)
  if (tid < 128) {
    floatx4 t = reinterpret_cast<const floatx4*>(kbias + (size_t)b * SK_)[tid];
    t += c2;                             // fold affine offset + fixed max
    reinterpret_cast<floatx4*>(bias_s)[tid] = t;
  }

  // Q fragments (B-operand) direct from f32
  short8 qf[4];
  for (int st = 0; st < 4; ++st) {
    float fv[8];
    for (int j = 0; j < 8; ++j)
      fv[j] = qsrc[(size_t)(st * 16 + hi * 8 + j) * SQ_];
    union { uint32_t u[4]; short8 s; } qk;
    for (int j2 = 0; j2 < 4; ++j2)
      qk.u[j2] = cvt_pk_bf16(fv[2 * j2], fv[2 * j2 + 1]);
    qf[st] = qk.s;
  }

  // ---- staging ----
  if (w < 8) {
    // K transpose from f32. Image element (r, d) lives at
    // r*64 + ((d>>3 ^ (r&7))<<3) + (d&7)  (matches read side below).
    const int dsub = l >> 3, ksub = l & 7;
    const float* kp0 = kfb + (size_t)(w * 8 + dsub) * SK_ + ksub;
#pragma unroll
    for (int t = 0; t < 8; ++t) {
      float fv[8];
#pragma unroll
      for (int kk = 0; kk < 8; ++kk)
        fv[kk] = kp0[t * 64 + kk * 8];
      short* kb = kbuf[t];
#pragma unroll
      for (int kk = 0; kk < 8; ++kk)
        kb[(kk * 8 + ksub) * 64 + ((w ^ ksub) << 3) + dsub] = f2bf(fv[kk]);
    }
  } else {
    // V from f32: identical swizzled image as the old gload16 path.
    const int rsub = l >> 3;
    const int c16s = (l & 7) ^ rsub;
    const int ck = w & 7;
#pragma unroll
    for (int t = 0; t < 8; ++t) {
      const float* vp = vbase + (size_t)(ck * 8 + rsub) * SK_ + t * 64 + c16s * 8;
      const float4 a = *reinterpret_cast<const float4*>(vp);
      const float4 c = *reinterpret_cast<const float4*>(vp + 4);
      union { uint32_t u[4]; short8 s; } pk;
      pk.u[0] = cvt_pk_bf16(a.x, a.y);
      pk.u[1] = cvt_pk_bf16(a.z, a.w);
      pk.u[2] = cvt_pk_bf16(c.x, c.y);
      pk.u[3] = cvt_pk_bf16(c.z, c.w);
      *reinterpret_cast<short8*>(&vbuf[t][ck * 512 + l * 8]) = pk.s;
    }
  }

  floatx16 oacc[2];
  for (int i = 0; i < 16; ++i) { oacc[0][i] = 0.f; oacc[1][i] = 0.f; }
  float lpart = 0.f;

  // single order-robust sync: all staging (loads + ds_writes + bias) done
  asm volatile("s_waitcnt vmcnt(0) lgkmcnt(0)" ::: "memory");
  __builtin_amdgcn_s_barrier();
  __builtin_amdgcn_sched_barrier(0);

#pragma unroll 1
  for (int it = 0; it < 8; ++it) {
    const int k0 = it * 64;
    const short* kl = kbuf[it];
    const short* vl = vbuf[it];

    // ---- S^T = K Q ----
    floatx16 s0, s1;
    for (int i = 0; i < 16; ++i) { s0[i] = 0.f; s1[i] = 0.f; }
    __builtin_amdgcn_s_setprio(1);
    for (int st = 0; st < 4; ++st) {
      const short8 ka = *reinterpret_cast<const short8*>(
          &kl[(size_t)l31 * 64 + (((st << 1) | hi) ^ swz) * 8]);
      s0 = __builtin_amdgcn_mfma_f32_32x32x16_bf16(ka, qf[st], s0, 0, 0, 0);
    }
    for (int st = 0; st < 4; ++st) {
      const short8 kb = *reinterpret_cast<const short8*>(
          &kl[(size_t)(32 + l31) * 64 + (((st << 1) | hi) ^ swz) * 8]);
      s1 = __builtin_amdgcn_mfma_f32_32x32x16_bf16(kb, qf[st], s1, 0, 0, 0);
    }
    __builtin_amdgcn_s_setprio(0);

    // P = exp2(s*a2 + bias)
    float p2[32];
    for (int sub = 0; sub < 2; ++sub)
      for (int gg = 0; gg < 4; ++gg) {
        const floatx4 bv = *reinterpret_cast<const floatx4*>(
            &bias_s[k0 + sub * 32 + gg * 8 + hi * 4]);
        for (int r = 0; r < 4; ++r) {
          const float sc = sub ? s1[gg * 4 + r] : s0[gg * 4 + r];
          p2[sub * 16 + gg * 4 + r] =
              __builtin_amdgcn_exp2f(__builtin_fmaf(sc, a2, bv[r]));
        }
      }

    // partial row-sum
    {
      float a16[16];
      for (int i = 0; i < 16; ++i) a16[i] = p2[i] + p2[i + 16];
      float a8[8];
      for (int i = 0; i < 8; ++i) a8[i] = a16[i] + a16[i + 8];
      lpart += ((a8[0] + a8[4]) + (a8[1] + a8[5])) + ((a8[2] + a8[6]) + (a8[3] + a8[7]));
    }

    // P -> bf16 words
    uint32_t Wd[16];
    for (int j = 0; j < 16; ++j) Wd[j] = cvt_pk_bf16(p2[2 * j], p2[2 * j + 1]);

    // PV with permlane32_swap cross-half exchange
    __builtin_amdgcn_s_setprio(1);
    for (int kc = 0; kc < 4; ++kc) {
      const int base = (kc >> 1) * 8 + (kc & 1) * 4;
      uint32_t x0 = Wd[base + 0], x1 = Wd[base + 1];
      uint32_t y0 = Wd[base + 2], y1 = Wd[base + 3];
      plane32_swap(x0, y0);
      plane32_swap(x1, y1);
      union { uint32_t u[4]; short8 s; } pk;
      pk.u[0] = x0; pk.u[1] = x1; pk.u[2] = y0; pk.u[3] = y1;
      const short8 pb = pk.s;
      const short8 va0 = *reinterpret_cast<const short8*>(
          &vl[(size_t)l31 * 64 + (((kc << 1) | hi) ^ swz) * 8]);
      const short8 va1 = *reinterpret_cast<const short8*>(
          &vl[(size_t)(32 + l31) * 64 + (((kc << 1) | hi) ^ swz) * 8]);
      oacc[0] = __builtin_amdgcn_mfma_f32_32x32x16_bf16(va0, pb, oacc[0], 0, 0, 0);
      oacc[1] = __builtin_amdgcn_mfma_f32_32x32x16_bf16(va1, pb, oacc[1], 0, 0, 0);
    }
    __builtin_amdgcn_s_setprio(0);
  }

  lpart += __shfl_xor(lpart, 32, 64);

  // epilogue
  const float invl = __builtin_amdgcn_rcpf(lpart);
  short* xr = xqT + ((size_t)bh * SQ_ + qidx) * 64;
  const float2* msvh = msv + h * DH_;
  for (int dt = 0; dt < 2; ++dt)
    for (int gg = 0; gg < 4; ++gg) {
      const int d0 = dt * 32 + gg * 8 + hi * 4;
      float qv[4];
      for (int r = 0; r < 4; ++r) qv[r] = qsrc[(size_t)(d0 + r) * SQ_];
      const float2 c0 = msvh[d0 + 0], c1 = msvh[d0 + 1],
                   c2v = msvh[d0 + 2], c3 = msvh[d0 + 3];
      short4 xv;
      xv.x = f2bf((qv[0] + oacc[dt][gg * 4 + 0] * invl) * c0.x - c0.y);
      xv.y = f2bf((qv[1] + oacc[dt][gg * 4 + 1] * invl) * c1.x - c1.y);
      xv.z = f2bf((qv[2] + oacc[dt][gg * 4 + 2] * invl) * c2v.x - c2v.y);
      xv.w = f2bf((qv[3] + oacc[dt][gg * 4 + 3] * invl) * c3.x - c3.y);
      *reinterpret_cast<short4*>(xr + d0) = xv;
    }
}

// proj (r12 shape): out[b,o,q] = silu(bias[o] + sum_d W[o,d] x[b,q,d]).
// 256 thr / 4 waves, 256o x 64q block, 64 KB swizzled x-tile in LDS.
__global__ __launch_bounds__(256) void proj_kernel(
    const short* __restrict__ Wb, const short* __restrict__ xT,
    const float* __restrict__ bias, float* __restrict__ out)
{
  __shared__ short xs[64 * 512];
  const int q0 = blockIdx.x * 64;
  const int o0 = blockIdx.y * 256;
  const int b  = blockIdx.z;
  const int tid = threadIdx.x, w = tid >> 6, l = tid & 63;
  const int l15 = l & 15, g = l >> 4;

  const short* xb = xT + (size_t)b * (H_ * SQ_ * 64);
  for (int hh = w * 2; hh < w * 2 + 2; ++hh) {
    const short* src = xb + ((size_t)hh * SQ_ + q0) * 64;
    for (int j = 0; j < 8; ++j) {
      const short8 val = *reinterpret_cast<const short8*>(src + j * 512 + l * 8);
      const int row = j * 8 + (l >> 3);
      const int c16 = (hh * 8 + (l & 7)) ^ (row & 7);
      *reinterpret_cast<short8*>(&xs[row * 512 + c16 * 8]) = val;
    }
  }
  __syncthreads();

  floatx4 acc[4][4];
  for (int ai = 0; ai < 4; ++ai)
    for (int bj = 0; bj < 4; ++bj)
      acc[ai][bj] = floatx4{0.f, 0.f, 0.f, 0.f};

  const short* wbase = Wb + (size_t)(o0 + w * 64 + l15) * D_;

  for (int step = 0; step < 16; ++step) {
    short8 af[4];
    for (int ai = 0; ai < 4; ++ai)
      af[ai] = *reinterpret_cast<const short8*>(
          wbase + (size_t)(ai * 16) * D_ + step * 32 + g * 8);
    short8 bf[4];
    for (int bj = 0; bj < 4; ++bj) {
      const int row = bj * 16 + l15;
      const int c16 = (step * 4 + g) ^ (row & 7);
      bf[bj] = *reinterpret_cast<const short8*>(&xs[row * 512 + c16 * 8]);
    }
    for (int ai = 0; ai < 4; ++ai)
      for (int bj = 0; bj < 4; ++bj)
        acc[ai][bj] = __builtin_amdgcn_mfma_f32_16x16x32_bf16(af[ai], bf[bj],
                                                              acc[ai][bj], 0, 0, 0);
  }

  for (int ai = 0; ai < 4; ++ai)
    for (int r = 0; r < 4; ++r) {
      const int o = o0 + w * 64 + ai * 16 + g * 4 + r;
      const float bo = bias[o];
      float* orow = out + ((size_t)b * D_ + o) * SQ_ + q0;
      for (int bj = 0; bj < 4; ++bj) {
        const float val = acc[ai][bj][r] + bo;
        const float e = __builtin_amdgcn_exp2f(-val * LOG2E_);
        orow[bj * 16 + l15] = val * __builtin_amdgcn_rcpf(1.0f + e);
      }
    }
}

extern "C" void kernel_launch(void* const* d_in, const int* in_sizes, int n_in,
                              void* d_out, int out_size, void* d_ws, size_t ws_size,
                              hipStream_t stream) {
  const float*   q     = (const float*)d_in[0];
  const float*   k     = (const float*)d_in[1];
  const float*   v     = (const float*)d_in[2];
  const uint8_t* mask  = (const uint8_t*)d_in[3];
  const float*   gamma = (const float*)d_in[4];
  const float*   beta  = (const float*)d_in[5];
  const float*   m_qk  = (const float*)d_in[6];
  const float*   s_qk  = (const float*)d_in[7];
  const float*   m_v   = (const float*)d_in[8];
  const float*   s_v   = (const float*)d_in[9];
  const float*   W     = (const float*)d_in[10];
  const float*   bias  = (const float*)d_in[11];
  float* out = (float*)d_out;

  char* ws = (char*)d_ws;
  short*  Wb    = (short*)ws;                                   // 512 KB
  short*  xqT   = (short*)(ws + (1u << 19));                    // 16 MB (x output)
  float2* msv   = (float2*)(ws + (1u << 19) + 3u * (1u << 24)); // 4 KB
  float*  kbias = (float*)(ws + (1u << 19) + 3u * (1u << 24) + 8192); // 64 KB

  smallprep_kernel<<<289, 256, 0, stream>>>(mask, kbias, m_v, s_v, msv, W, Wb);
  attn_kernel<<<256, 1024, 0, stream>>>(q, xqT, k, v, gamma, beta,
                                        m_qk, s_qk, msv, kbias);
  proj_kernel<<<dim3(8, 2, 32), 256, 0, stream>>>(Wb, xqT, bias, out);
}

// Round 23
// 65.573 us; speedup vs baseline: 3.0128x; 1.2907x over previous
//
#include <hip/hip_runtime.h>
#include <hip/hip_bf16.h>
#include <cstdint>
#include <cstddef>

typedef __attribute__((ext_vector_type(8))) short short8;
typedef __attribute__((ext_vector_type(4))) float floatx4;
typedef __attribute__((ext_vector_type(16))) float floatx16;

#define B_ 32
#define H_ 8
#define D_ 512
#define DH_ 64
#define SQ_ 512
#define SK_ 512
#define NEG_INF_ -1000000000.0f
#define LOG2E_ 1.4426950408889634f
#define FIXED_MAX_ 24.0f

__device__ __forceinline__ short f2bf(float f) {
  union { float f; uint32_t u; } x; x.f = f;
  uint32_t r = x.u + 0x7FFFu + ((x.u >> 16) & 1u);
  return (short)(r >> 16);
}
__device__ __forceinline__ uint32_t cvt_pk_bf16(float lo, float hi) {
  uint32_t r;
  asm("v_cvt_pk_bf16_f32 %0, %1, %2" : "=v"(r) : "v"(lo), "v"(hi));
  return r;
}
// Swap upper-half lanes of a with lower-half lanes of b (both modified).
__device__ __forceinline__ void plane32_swap(uint32_t& a, uint32_t& b) {
  asm("v_permlane32_swap_b32 %0, %1" : "+v"(a), "+v"(b));
}

// Swapped-operand 32x32 flash attention (r19/r22 structure) with ALL prep
// absorbed into the prologue:
//  - mask-layout flag: all 1024 threads scan 16 B each of the 16 KB mask,
//    one early __syncthreads.
//  - bias row (threads 0..127) built directly from mask, +c2 folded.
//  - msv for head h (threads 128..191) into LDS.
//  - W -> bf16 conversion distributed over blocks 0..63 (consumed by proj,
//    which launches after attn -> ordering safe).
// K and V staged from f32 up front (K-waves transpose via ds_write_b16,
// V-waves vector copy); single order-robust vmcnt(0)+lgkmcnt(0)+barrier;
// no in-loop sync. Compute loop byte-identical to r22.
__global__ __launch_bounds__(1024, 4) void attn_kernel(
    const float* __restrict__ qf32,     // [B][D][SQ] f32
    short* __restrict__ xqT,            // out x: [B][H][SQ][64] bf16
    const float* __restrict__ kf32,     // [B][D][SK] f32
    const float* __restrict__ vf32,     // [B][D][SK] f32
    const uint8_t* __restrict__ mask8,
    const float* __restrict__ gamma, const float* __restrict__ beta,
    const float* __restrict__ m_qk, const float* __restrict__ s_qk,
    const float* __restrict__ m_v, const float* __restrict__ s_v,
    const float* __restrict__ W, short* __restrict__ Wb)
{
  __shared__ float bias_s[SK_];
  __shared__ float2 msv_s[DH_];
  __shared__ int fnd;
  __shared__ short kbuf[8][4096];       // per 64-tile: [64 k-rows][64 d] swizzled
  __shared__ short vbuf[8][4096];       // per 64-tile: [64 d-rows][64 k] swizzled

  const int bh = blockIdx.x;            // 0..255
  const int h = bh & 7, b = bh >> 3;

  const int tid = threadIdx.x, w = tid >> 6, l = tid & 63;
  const int l31 = l & 31, hi = l >> 5;
  const int swz = l31 & 7;

  const float gh = gamma[h], be = beta[h], mq = m_qk[h], sq = s_qk[h];
  const float a2 = gh / (sq * 8.0f) * LOG2E_;
  const float c2 = (be - mq * gh / sq) * LOG2E_ - FIXED_MAX_;

  const int qidx = w * 32 + l31;
  const float* kfb = kf32 + ((size_t)b * D_ + h * DH_) * (size_t)SK_;
  const float* vbase = vf32 + ((size_t)b * D_ + h * DH_) * (size_t)SK_;
  const float* qsrc = qf32 + ((size_t)b * D_ + h * DH_) * (size_t)SQ_ + qidx;

  // ---- mask layout detect (whole 16 KB, 16 B per thread) ----
  if (tid == 0) fnd = 0;
  __syncthreads();
  {
    const uint4 m4 = *reinterpret_cast<const uint4*>(mask8 + tid * 16);
    // int32 layout of 0/1 has all bytes at offset%4!=0 equal to zero
    if ((m4.x & 0xFFFFFF00u) | (m4.y & 0xFFFFFF00u) |
        (m4.z & 0xFFFFFF00u) | (m4.w & 0xFFFFFF00u))
      atomicOr(&fnd, 1);
  }
  __syncthreads();
  const int fl = fnd;

  // ---- bias row (threads 0..127), msv (threads 128..191) ----
  if (tid < 128) {
    const int kk = tid * 4;
    int mx, my, mz, mw;
    if (fl) {
      const uchar4 mb = *reinterpret_cast<const uchar4*>(mask8 + (size_t)b * SK_ + kk);
      mx = mb.x; my = mb.y; mz = mb.z; mw = mb.w;
    } else {
      const int4 mi = reinterpret_cast<const int4*>(mask8)[(size_t)b * 128 + tid];
      mx = mi.x; my = mi.y; mz = mi.z; mw = mi.w;
    }
    floatx4 t;
    t[0] = mx ? NEG_INF_ * LOG2E_ + c2 : c2;
    t[1] = my ? NEG_INF_ * LOG2E_ + c2 : c2;
    t[2] = mz ? NEG_INF_ * LOG2E_ + c2 : c2;
    t[3] = mw ? NEG_INF_ * LOG2E_ + c2 : c2;
    reinterpret_cast<floatx4*>(bias_s)[tid] = t;
  } else if (tid < 192) {
    const int d = tid - 128;
    const float inv = 1.0f / s_v[h * DH_ + d];
    msv_s[d] = make_float2(inv, m_v[h * DH_ + d] * inv);
  }

  // ---- W -> bf16 (blocks 0..63, one float4 per thread) ----
  if (bh < 64) {
    const int i = bh * 1024 + tid;
    const float4 f = reinterpret_cast<const float4*>(W)[i];
    short4 s4;
    s4.x = f2bf(f.x); s4.y = f2bf(f.y); s4.z = f2bf(f.z); s4.w = f2bf(f.w);
    reinterpret_cast<short4*>(Wb)[i] = s4;
  }

  // Q fragments (B-operand) direct from f32
  short8 qf[4];
  for (int st = 0; st < 4; ++st) {
    float fv[8];
    for (int j = 0; j < 8; ++j)
      fv[j] = qsrc[(size_t)(st * 16 + hi * 8 + j) * SQ_];
    union { uint32_t u[4]; short8 s; } qk;
    for (int j2 = 0; j2 < 4; ++j2)
      qk.u[j2] = cvt_pk_bf16(fv[2 * j2], fv[2 * j2 + 1]);
    qf[st] = qk.s;
  }

  // ---- staging ----
  if (w < 8) {
    // K transpose from f32. Image element (r, d) lives at
    // r*64 + ((d>>3 ^ (r&7))<<3) + (d&7)  (matches read side below).
    const int dsub = l >> 3, ksub = l & 7;
    const float* kp0 = kfb + (size_t)(w * 8 + dsub) * SK_ + ksub;
#pragma unroll
    for (int t = 0; t < 8; ++t) {
      float fv[8];
#pragma unroll
      for (int kk = 0; kk < 8; ++kk)
        fv[kk] = kp0[t * 64 + kk * 8];
      short* kb = kbuf[t];
#pragma unroll
      for (int kk = 0; kk < 8; ++kk)
        kb[(kk * 8 + ksub) * 64 + ((w ^ ksub) << 3) + dsub] = f2bf(fv[kk]);
    }
  } else {
    // V from f32: identical swizzled image as the old gload16 path.
    const int rsub = l >> 3;
    const int c16s = (l & 7) ^ rsub;
    const int ck = w & 7;
#pragma unroll
    for (int t = 0; t < 8; ++t) {
      const float* vp = vbase + (size_t)(ck * 8 + rsub) * SK_ + t * 64 + c16s * 8;
      const float4 a = *reinterpret_cast<const float4*>(vp);
      const float4 c = *reinterpret_cast<const float4*>(vp + 4);
      union { uint32_t u[4]; short8 s; } pk;
      pk.u[0] = cvt_pk_bf16(a.x, a.y);
      pk.u[1] = cvt_pk_bf16(a.z, a.w);
      pk.u[2] = cvt_pk_bf16(c.x, c.y);
      pk.u[3] = cvt_pk_bf16(c.z, c.w);
      *reinterpret_cast<short8*>(&vbuf[t][ck * 512 + l * 8]) = pk.s;
    }
  }

  floatx16 oacc[2];
  for (int i = 0; i < 16; ++i) { oacc[0][i] = 0.f; oacc[1][i] = 0.f; }
  float lpart = 0.f;

  // single order-robust sync: all staging (loads + ds_writes + bias/msv) done
  asm volatile("s_waitcnt vmcnt(0) lgkmcnt(0)" ::: "memory");
  __builtin_amdgcn_s_barrier();
  __builtin_amdgcn_sched_barrier(0);

#pragma unroll 1
  for (int it = 0; it < 8; ++it) {
    const int k0 = it * 64;
    const short* kl = kbuf[it];
    const short* vl = vbuf[it];

    // ---- S^T = K Q ----
    floatx16 s0, s1;
    for (int i = 0; i < 16; ++i) { s0[i] = 0.f; s1[i] = 0.f; }
    __builtin_amdgcn_s_setprio(1);
    for (int st = 0; st < 4; ++st) {
      const short8 ka = *reinterpret_cast<const short8*>(
          &kl[(size_t)l31 * 64 + (((st << 1) | hi) ^ swz) * 8]);
      s0 = __builtin_amdgcn_mfma_f32_32x32x16_bf16(ka, qf[st], s0, 0, 0, 0);
    }
    for (int st = 0; st < 4; ++st) {
      const short8 kb = *reinterpret_cast<const short8*>(
          &kl[(size_t)(32 + l31) * 64 + (((st << 1) | hi) ^ swz) * 8]);
      s1 = __builtin_amdgcn_mfma_f32_32x32x16_bf16(kb, qf[st], s1, 0, 0, 0);
    }
    __builtin_amdgcn_s_setprio(0);

    // P = exp2(s*a2 + bias)
    float p2[32];
    for (int sub = 0; sub < 2; ++sub)
      for (int gg = 0; gg < 4; ++gg) {
        const floatx4 bv = *reinterpret_cast<const floatx4*>(
            &bias_s[k0 + sub * 32 + gg * 8 + hi * 4]);
        for (int r = 0; r < 4; ++r) {
          const float sc = sub ? s1[gg * 4 + r] : s0[gg * 4 + r];
          p2[sub * 16 + gg * 4 + r] =
              __builtin_amdgcn_exp2f(__builtin_fmaf(sc, a2, bv[r]));
        }
      }

    // partial row-sum
    {
      float a16[16];
      for (int i = 0; i < 16; ++i) a16[i] = p2[i] + p2[i + 16];
      float a8[8];
      for (int i = 0; i < 8; ++i) a8[i] = a16[i] + a16[i + 8];
      lpart += ((a8[0] + a8[4]) + (a8[1] + a8[5])) + ((a8[2] + a8[6]) + (a8[3] + a8[7]));
    }

    // P -> bf16 words
    uint32_t Wd[16];
    for (int j = 0; j < 16; ++j) Wd[j] = cvt_pk_bf16(p2[2 * j], p2[2 * j + 1]);

    // PV with permlane32_swap cross-half exchange
    __builtin_amdgcn_s_setprio(1);
    for (int kc = 0; kc < 4; ++kc) {
      const int base = (kc >> 1) * 8 + (kc & 1) * 4;
      uint32_t x0 = Wd[base + 0], x1 = Wd[base + 1];
      uint32_t y0 = Wd[base + 2], y1 = Wd[base + 3];
      plane32_swap(x0, y0);
      plane32_swap(x1, y1);
      union { uint32_t u[4]; short8 s; } pk;
      pk.u[0] = x0; pk.u[1] = x1; pk.u[2] = y0; pk.u[3] = y1;
      const short8 pb = pk.s;
      const short8 va0 = *reinterpret_cast<const short8*>(
          &vl[(size_t)l31 * 64 + (((kc << 1) | hi) ^ swz) * 8]);
      const short8 va1 = *reinterpret_cast<const short8*>(
          &vl[(size_t)(32 + l31) * 64 + (((kc << 1) | hi) ^ swz) * 8]);
      oacc[0] = __builtin_amdgcn_mfma_f32_32x32x16_bf16(va0, pb, oacc[0], 0, 0, 0);
      oacc[1] = __builtin_amdgcn_mfma_f32_32x32x16_bf16(va1, pb, oacc[1], 0, 0, 0);
    }
    __builtin_amdgcn_s_setprio(0);
  }

  lpart += __shfl_xor(lpart, 32, 64);

  // epilogue (msv from LDS)
  const float invl = __builtin_amdgcn_rcpf(lpart);
  short* xr = xqT + ((size_t)bh * SQ_ + qidx) * 64;
  for (int dt = 0; dt < 2; ++dt)
    for (int gg = 0; gg < 4; ++gg) {
      const int d0 = dt * 32 + gg * 8 + hi * 4;
      float qv[4];
      for (int r = 0; r < 4; ++r) qv[r] = qsrc[(size_t)(d0 + r) * SQ_];
      const float2 c0 = msv_s[d0 + 0], c1 = msv_s[d0 + 1],
                   c2v = msv_s[d0 + 2], c3 = msv_s[d0 + 3];
      short4 xv;
      xv.x = f2bf((qv[0] + oacc[dt][gg * 4 + 0] * invl) * c0.x - c0.y);
      xv.y = f2bf((qv[1] + oacc[dt][gg * 4 + 1] * invl) * c1.x - c1.y);
      xv.z = f2bf((qv[2] + oacc[dt][gg * 4 + 2] * invl) * c2v.x - c2v.y);
      xv.w = f2bf((qv[3] + oacc[dt][gg * 4 + 3] * invl) * c3.x - c3.y);
      *reinterpret_cast<short4*>(xr + d0) = xv;
    }
}

// proj (r12 shape): out[b,o,q] = silu(bias[o] + sum_d W[o,d] x[b,q,d]).
// 256 thr / 4 waves, 256o x 64q block, 64 KB swizzled x-tile in LDS.
__global__ __launch_bounds__(256) void proj_kernel(
    const short* __restrict__ Wb, const short* __restrict__ xT,
    const float* __restrict__ bias, float* __restrict__ out)
{
  __shared__ short xs[64 * 512];
  const int q0 = blockIdx.x * 64;
  const int o0 = blockIdx.y * 256;
  const int b  = blockIdx.z;
  const int tid = threadIdx.x, w = tid >> 6, l = tid & 63;
  const int l15 = l & 15, g = l >> 4;

  const short* xb = xT + (size_t)b * (H_ * SQ_ * 64);
  for (int hh = w * 2; hh < w * 2 + 2; ++hh) {
    const short* src = xb + ((size_t)hh * SQ_ + q0) * 64;
    for (int j = 0; j < 8; ++j) {
      const short8 val = *reinterpret_cast<const short8*>(src + j * 512 + l * 8);
      const int row = j * 8 + (l >> 3);
      const int c16 = (hh * 8 + (l & 7)) ^ (row & 7);
      *reinterpret_cast<short8*>(&xs[row * 512 + c16 * 8]) = val;
    }
  }
  __syncthreads();

  floatx4 acc[4][4];
  for (int ai = 0; ai < 4; ++ai)
    for (int bj = 0; bj < 4; ++bj)
      acc[ai][bj] = floatx4{0.f, 0.f, 0.f, 0.f};

  const short* wbase = Wb + (size_t)(o0 + w * 64 + l15) * D_;

  for (int step = 0; step < 16; ++step) {
    short8 af[4];
    for (int ai = 0; ai < 4; ++ai)
      af[ai] = *reinterpret_cast<const short8*>(
          wbase + (size_t)(ai * 16) * D_ + step * 32 + g * 8);
    short8 bf[4];
    for (int bj = 0; bj < 4; ++bj) {
      const int row = bj * 16 + l15;
      const int c16 = (step * 4 + g) ^ (row & 7);
      bf[bj] = *reinterpret_cast<const short8*>(&xs[row * 512 + c16 * 8]);
    }
    for (int ai = 0; ai < 4; ++ai)
      for (int bj = 0; bj < 4; ++bj)
        acc[ai][bj] = __builtin_amdgcn_mfma_f32_16x16x32_bf16(af[ai], bf[bj],
                                                              acc[ai][bj], 0, 0, 0);
  }

  for (int ai = 0; ai < 4; ++ai)
    for (int r = 0; r < 4; ++r) {
      const int o = o0 + w * 64 + ai * 16 + g * 4 + r;
      const float bo = bias[o];
      float* orow = out + ((size_t)b * D_ + o) * SQ_ + q0;
      for (int bj = 0; bj < 4; ++bj) {
        const float val = acc[ai][bj][r] + bo;
        const float e = __builtin_amdgcn_exp2f(-val * LOG2E_);
        orow[bj * 16 + l15] = val * __builtin_amdgcn_rcpf(1.0f + e);
      }
    }
}

extern "C" void kernel_launch(void* const* d_in, const int* in_sizes, int n_in,
                              void* d_out, int out_size, void* d_ws, size_t ws_size,
                              hipStream_t stream) {
  const float*   q     = (const float*)d_in[0];
  const float*   k     = (const float*)d_in[1];
  const float*   v     = (const float*)d_in[2];
  const uint8_t* mask  = (const uint8_t*)d_in[3];
  const float*   gamma = (const float*)d_in[4];
  const float*   beta  = (const float*)d_in[5];
  const float*   m_qk  = (const float*)d_in[6];
  const float*   s_qk  = (const float*)d_in[7];
  const float*   m_v   = (const float*)d_in[8];
  const float*   s_v   = (const float*)d_in[9];
  const float*   W     = (const float*)d_in[10];
  const float*   bias  = (const float*)d_in[11];
  float* out = (float*)d_out;

  char* ws = (char*)d_ws;
  short*  Wb  = (short*)ws;                                   // 512 KB
  short*  xqT = (short*)(ws + (1u << 19));                    // 16 MB (x output)

  attn_kernel<<<256, 1024, 0, stream>>>(q, xqT, k, v, mask, gamma, beta,
                                        m_qk, s_qk, m_v, s_v, W, Wb);
  proj_kernel<<<dim3(8, 2, 32), 256, 0, stream>>>(Wb, xqT, bias, out);
}